// Round 1
// baseline (1182.246 us; speedup 1.0000x reference)
//
#include <hip/hip_runtime.h>

// VQ-VAE forward on MI355X.
// Outputs concatenated in d_out (fp32): out[4194304] | loss[1] | perplexity[1] | idx_as_float[16384]
//
// Pipeline:
//  1. init          : zero counts + loss accumulator (ws is poisoned each call)
//  2. prep_w        : weight fp32 -> (w_hi, w_lo) fp16 split + wsq
//  3. gemm_argmin   : MFMA fp16 3-product distance scores, per-row top-2 (per N-split)
//  4. combine       : merge splits' top-2, fp64 rescore the 2 candidates -> exact idx,
//                     histogram atomics, idx-as-float output
//  5. gather_loss   : out = weight[idx] (transposed write), commitment-loss partial sums
//  6. finalize      : perplexity from counts, loss scale

#define M_TOTAL 16384
#define N_CODES 8192
#define KDIM    256
#define SPATIAL 4096   // 16*16*16 per batch
#define NSPLIT  2

typedef _Float16 v8hf __attribute__((ext_vector_type(8)));
typedef _Float16 v4hf __attribute__((ext_vector_type(4)));
typedef float    v4f  __attribute__((ext_vector_type(4)));

// ---------------------------------------------------------------- init
__global__ void init_kernel(int* __restrict__ counts, float* __restrict__ loss_acc) {
    int i = blockIdx.x * blockDim.x + threadIdx.x;
    if (i < N_CODES) counts[i] = 0;
    if (i == 0) *loss_acc = 0.0f;
}

// ---------------------------------------------------------------- prep_w
// one wave per code row: fp16 hi/lo split + |w|^2
__global__ void prep_w_kernel(const float* __restrict__ w,
                              _Float16* __restrict__ w_hi,
                              _Float16* __restrict__ w_lo,
                              float* __restrict__ wsq) {
    int n = blockIdx.x;
    int lane = threadIdx.x;  // 64
    const v4f* wp = (const v4f*)(w + (size_t)n * KDIM);
    v4f v = wp[lane];
    v4hf hv, lv;
    float s = 0.0f;
#pragma unroll
    for (int j = 0; j < 4; j++) {
        float f = v[j];
        s += f * f;
        _Float16 h = (_Float16)f;
        hv[j] = h;
        lv[j] = (_Float16)(f - (float)h);
    }
    *(v4hf*)(w_hi + (size_t)n * KDIM + lane * 4) = hv;
    *(v4hf*)(w_lo + (size_t)n * KDIM + lane * 4) = lv;
#pragma unroll
    for (int off = 32; off >= 1; off >>= 1) s += __shfl_xor(s, off);
    if (lane == 0) wsq[n] = s;
}

// ---------------------------------------------------------------- top-2 merge helper
__device__ __forceinline__ void top2_merge(float& v1, int& i1, float& v2, int& i2,
                                           float o1, int oi1, float o2, int oi2) {
    bool ob = (o1 < v1) || (o1 == v1 && oi1 < i1);
    float n1v, n2v; int n1i, n2i;
    if (ob) {
        bool t = (v1 < o2) || (v1 == o2 && i1 < oi2);
        n1v = o1; n1i = oi1;
        n2v = t ? v1 : o2; n2i = t ? i1 : oi2;
    } else {
        bool t = (o1 < v2) || (o1 == v2 && oi1 < i2);
        n1v = v1; n1i = i1;
        n2v = t ? o1 : v2; n2i = t ? oi1 : i2;
    }
    v1 = n1v; i1 = n1i; v2 = n2v; i2 = n2i;
}

// ---------------------------------------------------------------- gemm + argmin top2
// block: 256 thr (4 waves), 64 rows. grid: (256 row-blocks, NSPLIT).
// Wave w handles rows i0 + w*16 .. +16, all 4096 codes of its split in chunks of 64.
// A fragments (z hi/lo, fp16) live in registers for the whole block: 64 VGPRs/lane.
__global__ __launch_bounds__(256, 2) void gemm_argmin_kernel(
    const float* __restrict__ z,
    const _Float16* __restrict__ w_hi, const _Float16* __restrict__ w_lo,
    const float* __restrict__ wsq,
    float* __restrict__ t2v1, int* __restrict__ t2i1,
    float* __restrict__ t2v2, int* __restrict__ t2i2)
{
    const int rb    = blockIdx.x;
    const int split = blockIdx.y;
    const int i0    = rb * 64;
    const int b     = i0 >> 12;        // batch
    const int s0    = i0 & (SPATIAL - 1);
    const int tid   = threadIdx.x;
    const int wave  = tid >> 6;
    const int lane  = tid & 63;
    const int r     = lane & 15;       // m (A) / n (B) within 16-tile
    const int q     = lane >> 4;       // quad -> k = q*8 + j

    // ---- load A fragments once (z is (b, c=k, s); row = b*4096 + s) ----
    v8hf a_hi[8], a_lo[8];
    {
        const float* zb = z + ((size_t)b << 20) + (size_t)(s0 + wave * 16 + r);
#pragma unroll
        for (int ks = 0; ks < 8; ks++) {
            const int kbase = ks * 32 + q * 8;
#pragma unroll
            for (int j = 0; j < 8; j++) {
                float f = zb[(size_t)(kbase + j) << 12];
                _Float16 h = (_Float16)f;
                a_hi[ks][j] = h;
                a_lo[ks][j] = (_Float16)(f - (float)h);
            }
        }
    }

    float v1[4], v2[4];
    int   i1[4], i2[4];
#pragma unroll
    for (int g = 0; g < 4; g++) { v1[g] = 3.4e38f; v2[g] = 3.4e38f; i1[g] = 0x7fffffff; i2[g] = 0x7fffffff; }

    const size_t lane_boff = (size_t)r * KDIM + (size_t)q * 8;

    for (int ci = 0; ci < 64; ci++) {
        const int nbase = (split << 12) + (ci << 6);
        const _Float16* bh = w_hi + (size_t)nbase * KDIM + lane_boff;
        const _Float16* bl = w_lo + (size_t)nbase * KDIM + lane_boff;

        v4f acc[4];
#pragma unroll
        for (int st = 0; st < 4; st++) acc[st] = (v4f){0.f, 0.f, 0.f, 0.f};

#pragma unroll
        for (int ks = 0; ks < 8; ks++) {
#pragma unroll
            for (int st = 0; st < 4; st++) {
                v8hf bhf = *(const v8hf*)(bh + (size_t)st * 16 * KDIM + ks * 32);
                v8hf blf = *(const v8hf*)(bl + (size_t)st * 16 * KDIM + ks * 32);
                acc[st] = __builtin_amdgcn_mfma_f32_16x16x32_f16(a_hi[ks], bhf, acc[st], 0, 0, 0);
                acc[st] = __builtin_amdgcn_mfma_f32_16x16x32_f16(a_lo[ks], bhf, acc[st], 0, 0, 0);
                acc[st] = __builtin_amdgcn_mfma_f32_16x16x32_f16(a_hi[ks], blf, acc[st], 0, 0, 0);
            }
        }

        // epilogue: score = |w|^2 - 2*dot; per-lane running top-2 (n ascending -> strict <)
#pragma unroll
        for (int st = 0; st < 4; st++) {
            const int n = nbase + st * 16 + r;
            const float wn = wsq[n];
#pragma unroll
            for (int g = 0; g < 4; g++) {
                float s = __builtin_fmaf(-2.0f, acc[st][g], wn);
                if (s < v1[g])      { v2[g] = v1[g]; i2[g] = i1[g]; v1[g] = s; i1[g] = n; }
                else if (s < v2[g]) { v2[g] = s; i2[g] = n; }
            }
        }
    }

    // cross-lane top-2 reduce over the 16 n-lanes (lanes sharing q)
#pragma unroll
    for (int off = 1; off < 16; off <<= 1) {
#pragma unroll
        for (int g = 0; g < 4; g++) {
            float o1 = __shfl_xor(v1[g], off);
            int  oi1 = __shfl_xor(i1[g], off);
            float o2 = __shfl_xor(v2[g], off);
            int  oi2 = __shfl_xor(i2[g], off);
            top2_merge(v1[g], i1[g], v2[g], i2[g], o1, oi1, o2, oi2);
        }
    }

    if (r == 0) {
        const int rowbase = i0 + wave * 16 + q * 4;
#pragma unroll
        for (int g = 0; g < 4; g++) {
            const size_t o = (size_t)split * M_TOTAL + (rowbase + g);
            t2v1[o] = v1[g]; t2i1[o] = i1[g];
            t2v2[o] = v2[g]; t2i2[o] = i2[g];
        }
    }
}

// ---------------------------------------------------------------- combine + fp64 rescore
__global__ void combine_kernel(const float* __restrict__ z,
                               const float* __restrict__ weight,
                               const float* __restrict__ t2v1, const int* __restrict__ t2i1,
                               const float* __restrict__ t2v2, const int* __restrict__ t2i2,
                               int* __restrict__ idx_final, int* __restrict__ counts,
                               float* __restrict__ out_idx_f)
{
    int i = blockIdx.x * blockDim.x + threadIdx.x;   // 16384 rows
    float v1 = t2v1[i]; int i1 = t2i1[i];
    float v2 = t2v2[i]; int i2 = t2i2[i];
    top2_merge(v1, i1, v2, i2,
               t2v1[M_TOTAL + i], t2i1[M_TOTAL + i],
               t2v2[M_TOTAL + i], t2i2[M_TOTAL + i]);

    // exact fp64 distance for the two candidates
    const int bb = i >> 12, ss = i & (SPATIAL - 1);
    const float* zrow = z + ((size_t)bb << 20) + ss;       // stride 4096 along k
    const float* w1 = weight + (size_t)i1 * KDIM;
    const float* w2 = weight + (size_t)i2 * KDIM;
    double d1 = 0.0, d2 = 0.0;
    for (int k4 = 0; k4 < KDIM / 4; k4++) {
        v4f wv1 = *(const v4f*)(w1 + k4 * 4);
        v4f wv2 = *(const v4f*)(w2 + k4 * 4);
#pragma unroll
        for (int j = 0; j < 4; j++) {
            double zk = (double)zrow[(size_t)(k4 * 4 + j) << 12];
            double q1 = zk - (double)wv1[j];
            double q2 = zk - (double)wv2[j];
            d1 += q1 * q1; d2 += q2 * q2;
        }
    }
    int fi = (d1 < d2 || (d1 == d2 && i1 < i2)) ? i1 : i2;
    idx_final[i] = fi;
    out_idx_f[i] = (float)fi;
    atomicAdd(&counts[fi], 1);
}

// ---------------------------------------------------------------- gather + loss
// block: 32 rows, 256 thr. Stage the 32 gathered codebook rows in LDS (coalesced reads),
// then write out in (b,c,s) layout (coalesced along s) and accumulate (w - z)^2.
__global__ __launch_bounds__(256) void gather_loss_kernel(
    const float* __restrict__ z, const float* __restrict__ weight,
    const int* __restrict__ idx_final, float* __restrict__ out,
    float* __restrict__ loss_acc)
{
    __shared__ float lds_w[32][KDIM + 1];
    const int i0 = blockIdx.x * 32;
    const int b  = i0 >> 12;
    const int s0 = i0 & (SPATIAL - 1);
    const int t  = threadIdx.x;

    for (int e = t; e < 32 * KDIM; e += 256) {
        int rr = e >> 8, c = e & 255;
        lds_w[rr][c] = weight[(size_t)idx_final[i0 + rr] * KDIM + c];
    }
    __syncthreads();

    const int m  = t & 31;
    const int c0 = t >> 5;     // 8 c-values per iteration
    const size_t base = ((size_t)b << 20) + (size_t)(s0 + m);
    float accl = 0.0f;
    for (int c = c0; c < KDIM; c += 8) {
        float wv = lds_w[m][c];
        float zv = z[base + ((size_t)c << 12)];
        float d = wv - zv;
        accl += d * d;
        out[base + ((size_t)c << 12)] = wv;
    }
#pragma unroll
    for (int off = 32; off >= 1; off >>= 1) accl += __shfl_xor(accl, off);
    __shared__ float wsum[4];
    if ((t & 63) == 0) wsum[t >> 6] = accl;
    __syncthreads();
    if (t == 0) atomicAdd(loss_acc, wsum[0] + wsum[1] + wsum[2] + wsum[3]);
}

// ---------------------------------------------------------------- finalize
__global__ void finalize_kernel(const int* __restrict__ counts,
                                const float* __restrict__ loss_acc,
                                float* __restrict__ out_scalars)
{
    const int t = threadIdx.x;
    double s = 0.0;
    for (int n = t; n < N_CODES; n += 256) {
        double p = (double)counts[n] / (double)M_TOTAL;
        s -= p * log(p + 1e-10);
    }
#pragma unroll
    for (int off = 32; off >= 1; off >>= 1) s += __shfl_xor(s, off);
    __shared__ double sds[4];
    if ((t & 63) == 0) sds[t >> 6] = s;
    __syncthreads();
    if (t == 0) {
        double tot = sds[0] + sds[1] + sds[2] + sds[3];
        out_scalars[0] = (float)(0.25 * (double)(*loss_acc) / (double)(M_TOTAL * KDIM));
        out_scalars[1] = (float)exp(tot);
    }
}

// ---------------------------------------------------------------- launch
extern "C" void kernel_launch(void* const* d_in, const int* in_sizes, int n_in,
                              void* d_out, int out_size, void* d_ws, size_t ws_size,
                              hipStream_t stream) {
    const float* z      = (const float*)d_in[0];   // 4*256*16*16*16
    const float* weight = (const float*)d_in[1];   // 8192*256
    float* out = (float*)d_out;

    // workspace carve-up (~9.2 MB)
    size_t off = 0;
    auto carve = [&](size_t bytes) {
        void* p = (char*)d_ws + off;
        off += (bytes + 255) & ~(size_t)255;
        return p;
    };
    _Float16* w_hi   = (_Float16*)carve((size_t)N_CODES * KDIM * 2);
    _Float16* w_lo   = (_Float16*)carve((size_t)N_CODES * KDIM * 2);
    float*    wsq    = (float*)   carve((size_t)N_CODES * 4);
    float*    t2v1   = (float*)   carve((size_t)NSPLIT * M_TOTAL * 4);
    int*      t2i1   = (int*)     carve((size_t)NSPLIT * M_TOTAL * 4);
    float*    t2v2   = (float*)   carve((size_t)NSPLIT * M_TOTAL * 4);
    int*      t2i2   = (int*)     carve((size_t)NSPLIT * M_TOTAL * 4);
    int*      idxf   = (int*)     carve((size_t)M_TOTAL * 4);
    int*      counts = (int*)     carve((size_t)N_CODES * 4);
    float*    lossac = (float*)   carve(16);

    float* out_scalars = out + (size_t)4 * KDIM * SPATIAL;       // [loss, perplexity]
    float* out_idx_f   = out_scalars + 2;                        // 16384 idx as float

    init_kernel<<<dim3((N_CODES + 255) / 256), dim3(256), 0, stream>>>(counts, lossac);
    prep_w_kernel<<<dim3(N_CODES), dim3(64), 0, stream>>>(weight, w_hi, w_lo, wsq);
    gemm_argmin_kernel<<<dim3(M_TOTAL / 64, NSPLIT), dim3(256), 0, stream>>>(
        z, w_hi, w_lo, wsq, t2v1, t2i1, t2v2, t2i2);
    combine_kernel<<<dim3(M_TOTAL / 256), dim3(256), 0, stream>>>(
        z, weight, t2v1, t2i1, t2v2, t2i2, idxf, counts, out_idx_f);
    gather_loss_kernel<<<dim3(M_TOTAL / 32), dim3(256), 0, stream>>>(
        z, weight, idxf, out, lossac);
    finalize_kernel<<<dim3(1), dim3(256), 0, stream>>>(counts, lossac, out_scalars);
}

// Round 2
// 318.552 us; speedup vs baseline: 3.7113x; 3.7113x over previous
//
#include <hip/hip_runtime.h>

// VQ-VAE forward on MI355X.
// d_out (fp32): out[4194304] | loss[1] | perplexity[1] | idx_as_float[16384]
//
// Round 2: gemm_argmin restructured — B (w hi/lo fp16, swizzled+chunk-packed in
// global by prep_w) is staged per 32-code chunk into double-buffered LDS via
// global_load_lds(16B) and shared by all 4 waves; 32 rows/wave (A in 128 VGPRs);
// grid 512 with XCD-aware split assignment so each XCD's L2 holds its split.

#define M_TOTAL 16384
#define N_CODES 8192
#define KDIM    256
#define SPATIAL 4096            // 16*16*16 per batch
#define NSPLIT  4
#define NB      32              // codes per LDS chunk
#define CODES_PER_SPLIT  2048
#define CHUNKS_PER_SPLIT 64     // 2048/32
#define CHUNK_BYTES      32768  // 32 codes * 256 dims * 2B * (hi+lo)

typedef _Float16 v8hf __attribute__((ext_vector_type(8)));
typedef _Float16 v4hf __attribute__((ext_vector_type(4)));
typedef float    v4f  __attribute__((ext_vector_type(4)));

// ---------------------------------------------------------------- init
__global__ void init_kernel(int* __restrict__ counts, float* __restrict__ loss_acc) {
    int i = blockIdx.x * blockDim.x + threadIdx.x;
    if (i < N_CODES) counts[i] = 0;
    if (i == 0) *loss_acc = 0.0f;
}

// ---------------------------------------------------------------- prep_w
// one wave per code row: fp16 hi/lo split + |w|^2, written CHUNK-PACKED + SWIZZLED:
// chunk c (32 codes) occupies [c*32KB, +32KB): [hi 32x512B][lo 32x512B].
// Within a 512B row, 16B granule g is stored at slot g XOR (code&7) so that the
// gemm kernel's ds_read_b128 pattern (16 code-lanes x 4 quad-lanes) is conflict-free.
__global__ void prep_w_kernel(const float* __restrict__ w,
                              _Float16* __restrict__ wpk,
                              float* __restrict__ wsq) {
    int n = blockIdx.x;
    int lane = threadIdx.x;  // 64
    v4f v = ((const v4f*)(w + (size_t)n * KDIM))[lane];
    v4hf hv, lv;
    float s = 0.0f;
#pragma unroll
    for (int j = 0; j < 4; j++) {
        float f = v[j];
        s += f * f;
        _Float16 h = (_Float16)f;
        hv[j] = h;
        lv[j] = (_Float16)(f - (float)h);
    }
    const int d = lane * 4;          // element index 0..255
    const int g = d >> 3;            // 16B granule 0..31
    const int sub = d & 7;           // element within granule
    size_t h_off = (size_t)(n >> 5) * 16384          // chunk, in halfs (32KB)
                 + (size_t)(n & 31) * 256            // row within chunk (512B)
                 + ((g ^ (n & 7)) << 3) + sub;       // swizzled granule
    *(v4hf*)(wpk + h_off)        = hv;               // hi
    *(v4hf*)(wpk + h_off + 8192) = lv;               // lo half of chunk (+16KB)
#pragma unroll
    for (int off = 32; off >= 1; off >>= 1) s += __shfl_xor(s, off);
    if (lane == 0) wsq[n] = s;
}

// ---------------------------------------------------------------- top-2 merge helper
__device__ __forceinline__ void top2_merge(float& v1, int& i1, float& v2, int& i2,
                                           float o1, int oi1, float o2, int oi2) {
    bool ob = (o1 < v1) || (o1 == v1 && oi1 < i1);
    float n1v, n2v; int n1i, n2i;
    if (ob) {
        bool t = (v1 < o2) || (v1 == o2 && i1 < oi2);
        n1v = o1; n1i = oi1;
        n2v = t ? v1 : o2; n2i = t ? i1 : oi2;
    } else {
        bool t = (o1 < v2) || (o1 == v2 && oi1 < i2);
        n1v = v1; n1i = i1;
        n2v = t ? o1 : v2; n2i = t ? oi1 : i2;
    }
    v1 = n1v; i1 = n1i; v2 = n2v; i2 = n2i;
}

// ---------------------------------------------------------------- gemm + argmin top2
// block: 256 thr (4 waves), 128 rows (32/wave = 2 m-tiles); sweeps its split's
// 2048 codes in 64 chunks of 32, B staged in double-buffered LDS.
__global__ __launch_bounds__(256, 2) void gemm_argmin_kernel(
    const float* __restrict__ z,
    const _Float16* __restrict__ wpk,
    const float* __restrict__ wsq,
    float* __restrict__ t2v1, int* __restrict__ t2i1,
    float* __restrict__ t2v2, int* __restrict__ t2i2)
{
    __shared__ __align__(16) _Float16 ldsb[2][16384];   // 2 x 32KB
    __shared__ float wsq_s[CODES_PER_SPLIT];            // 8KB

    const int bid   = blockIdx.x;
    const int slot  = bid & 7;                 // ~XCD id (dispatch round-robin)
    const int split = slot >> 1;               // 2 XCDs per split -> split fits L2
    const int rb    = ((bid >> 3) << 1) | (slot & 1);   // 0..127
    const int i0    = rb * 128;
    const int b     = i0 >> 12;
    const int s0    = i0 & (SPATIAL - 1);
    const int tid   = threadIdx.x;
    const int wave  = tid >> 6;
    const int lane  = tid & 63;
    const int r     = lane & 15;
    const int q     = lane >> 4;

    // ---- stage chunk 0 immediately (loads in flight during A setup) ----
    const char* wb = (const char*)wpk;
    auto stage = [&](int chunk, int buf) {
        const char* gb = wb + (size_t)(split * CHUNKS_PER_SPLIT + chunk) * CHUNK_BYTES
                            + wave * 8192 + lane * 16;
        _Float16* lb = &ldsb[buf][wave * 4096];
#pragma unroll
        for (int j = 0; j < 8; j++) {
            __builtin_amdgcn_global_load_lds(
                (const __attribute__((address_space(1))) void*)(gb + j * 1024),
                (__attribute__((address_space(3))) void*)(lb + j * 512), 16, 0, 0);
        }
    };
    stage(0, 0);

    for (int t = tid; t < CODES_PER_SPLIT; t += 256)
        wsq_s[t] = wsq[split * CODES_PER_SPLIT + t];

    // ---- A fragments: 2 m-tiles x 8 ks, hi/lo (128 VGPRs) ----
    v8hf a_hi[2][8], a_lo[2][8];
    {
        const float* zb = z + ((size_t)b << 20) + (size_t)(s0 + wave * 32 + r);
#pragma unroll
        for (int mt = 0; mt < 2; mt++) {
#pragma unroll
            for (int ks = 0; ks < 8; ks++) {
                const int kbase = ks * 32 + q * 8;
#pragma unroll
                for (int j = 0; j < 8; j++) {
                    float f = zb[((size_t)(kbase + j) << 12) + mt * 16];
                    _Float16 h = (_Float16)f;
                    a_hi[mt][ks][j] = h;
                    a_lo[mt][ks][j] = (_Float16)(f - (float)h);
                }
            }
        }
    }

    float v1[2][4], v2[2][4];
    int   i1[2][4], i2[2][4];
#pragma unroll
    for (int mt = 0; mt < 2; mt++)
#pragma unroll
    for (int g = 0; g < 4; g++) {
        v1[mt][g] = 3.4e38f; v2[mt][g] = 3.4e38f;
        i1[mt][g] = 0x7fffffff; i2[mt][g] = 0x7fffffff;
    }

    const int swz = r & 7;

    for (int it = 0; it < CHUNKS_PER_SPLIT; it++) {
        const int buf = it & 1;
        __syncthreads();                       // chunk `it` landed; prev buf consumed
        if (it + 1 < CHUNKS_PER_SPLIT) stage(it + 1, buf ^ 1);

        v4f acc[2][2];
#pragma unroll
        for (int mt = 0; mt < 2; mt++)
#pragma unroll
        for (int st = 0; st < 2; st++) acc[mt][st] = (v4f){0.f, 0.f, 0.f, 0.f};

        const _Float16* Lbase = &ldsb[buf][0];
#pragma unroll
        for (int st = 0; st < 2; st++) {
            const int rowoff = (st * 16 + r) * 256;     // halfs
#pragma unroll
            for (int ks = 0; ks < 8; ks++) {
                const int gran = ((ks << 2) | q) ^ swz;
                const _Float16* ph = Lbase + rowoff + (gran << 3);
                v8hf bh = *(const v8hf*)ph;
                v8hf bl = *(const v8hf*)(ph + 8192);    // lo matrix (+16KB)
#pragma unroll
                for (int mt = 0; mt < 2; mt++) {
                    acc[mt][st] = __builtin_amdgcn_mfma_f32_16x16x32_f16(a_hi[mt][ks], bh, acc[mt][st], 0, 0, 0);
                    acc[mt][st] = __builtin_amdgcn_mfma_f32_16x16x32_f16(a_lo[mt][ks], bh, acc[mt][st], 0, 0, 0);
                    acc[mt][st] = __builtin_amdgcn_mfma_f32_16x16x32_f16(a_hi[mt][ks], bl, acc[mt][st], 0, 0, 0);
                }
            }
        }

        // epilogue: score = |w|^2 - 2*dot; running top-2 (n ascending -> strict <)
#pragma unroll
        for (int st = 0; st < 2; st++) {
            const int nl = (it << 5) + st * 16 + r;
            const float wn = wsq_s[nl];
            const int n = split * CODES_PER_SPLIT + nl;
#pragma unroll
            for (int mt = 0; mt < 2; mt++)
#pragma unroll
            for (int g = 0; g < 4; g++) {
                float s = __builtin_fmaf(-2.0f, acc[mt][st][g], wn);
                if (s < v1[mt][g])      { v2[mt][g] = v1[mt][g]; i2[mt][g] = i1[mt][g];
                                          v1[mt][g] = s; i1[mt][g] = n; }
                else if (s < v2[mt][g]) { v2[mt][g] = s; i2[mt][g] = n; }
            }
        }
    }

    // cross-lane top-2 reduce over the 16 n-lanes (lanes sharing q)
#pragma unroll
    for (int off = 1; off < 16; off <<= 1) {
#pragma unroll
        for (int mt = 0; mt < 2; mt++)
#pragma unroll
        for (int g = 0; g < 4; g++) {
            float o1 = __shfl_xor(v1[mt][g], off);
            int  oi1 = __shfl_xor(i1[mt][g], off);
            float o2 = __shfl_xor(v2[mt][g], off);
            int  oi2 = __shfl_xor(i2[mt][g], off);
            top2_merge(v1[mt][g], i1[mt][g], v2[mt][g], i2[mt][g], o1, oi1, o2, oi2);
        }
    }

    if (r == 0) {
#pragma unroll
        for (int mt = 0; mt < 2; mt++) {
            const int rowbase = i0 + wave * 32 + mt * 16 + q * 4;
#pragma unroll
            for (int g = 0; g < 4; g++) {
                const size_t o = (size_t)split * M_TOTAL + (rowbase + g);
                t2v1[o] = v1[mt][g]; t2i1[o] = i1[mt][g];
                t2v2[o] = v2[mt][g]; t2i2[o] = i2[mt][g];
            }
        }
    }
}

// ---------------------------------------------------------------- combine + fp64 rescore
__global__ void combine_kernel(const float* __restrict__ z,
                               const float* __restrict__ weight,
                               const float* __restrict__ t2v1, const int* __restrict__ t2i1,
                               const float* __restrict__ t2v2, const int* __restrict__ t2i2,
                               int* __restrict__ idx_final, int* __restrict__ counts,
                               float* __restrict__ out_idx_f)
{
    int i = blockIdx.x * blockDim.x + threadIdx.x;   // 16384 rows
    float v1 = t2v1[i]; int i1 = t2i1[i];
    float v2 = t2v2[i]; int i2 = t2i2[i];
#pragma unroll
    for (int s = 1; s < NSPLIT; s++) {
        top2_merge(v1, i1, v2, i2,
                   t2v1[(size_t)s * M_TOTAL + i], t2i1[(size_t)s * M_TOTAL + i],
                   t2v2[(size_t)s * M_TOTAL + i], t2i2[(size_t)s * M_TOTAL + i]);
    }

    // exact fp64 distance for the two candidates
    const int bb = i >> 12, ss = i & (SPATIAL - 1);
    const float* zrow = z + ((size_t)bb << 20) + ss;       // stride 4096 along k
    const float* w1 = weight + (size_t)i1 * KDIM;
    const float* w2 = weight + (size_t)i2 * KDIM;
    double d1 = 0.0, d2 = 0.0;
    for (int k4 = 0; k4 < KDIM / 4; k4++) {
        v4f wv1 = *(const v4f*)(w1 + k4 * 4);
        v4f wv2 = *(const v4f*)(w2 + k4 * 4);
#pragma unroll
        for (int j = 0; j < 4; j++) {
            double zk = (double)zrow[(size_t)(k4 * 4 + j) << 12];
            double q1 = zk - (double)wv1[j];
            double q2 = zk - (double)wv2[j];
            d1 += q1 * q1; d2 += q2 * q2;
        }
    }
    int fi = (d1 < d2 || (d1 == d2 && i1 < i2)) ? i1 : i2;
    idx_final[i] = fi;
    out_idx_f[i] = (float)fi;
    atomicAdd(&counts[fi], 1);
}

// ---------------------------------------------------------------- gather + loss
__global__ __launch_bounds__(256) void gather_loss_kernel(
    const float* __restrict__ z, const float* __restrict__ weight,
    const int* __restrict__ idx_final, float* __restrict__ out,
    float* __restrict__ loss_acc)
{
    __shared__ float lds_w[32][KDIM + 1];
    const int i0 = blockIdx.x * 32;
    const int b  = i0 >> 12;
    const int s0 = i0 & (SPATIAL - 1);
    const int t  = threadIdx.x;

    for (int e = t; e < 32 * KDIM; e += 256) {
        int rr = e >> 8, c = e & 255;
        lds_w[rr][c] = weight[(size_t)idx_final[i0 + rr] * KDIM + c];
    }
    __syncthreads();

    const int m  = t & 31;
    const int c0 = t >> 5;     // 8 c-values per iteration
    const size_t base = ((size_t)b << 20) + (size_t)(s0 + m);
    float accl = 0.0f;
    for (int c = c0; c < KDIM; c += 8) {
        float wv = lds_w[m][c];
        float zv = z[base + ((size_t)c << 12)];
        float d = wv - zv;
        accl += d * d;
        out[base + ((size_t)c << 12)] = wv;
    }
#pragma unroll
    for (int off = 32; off >= 1; off >>= 1) accl += __shfl_xor(accl, off);
    __shared__ float wsum[4];
    if ((t & 63) == 0) wsum[t >> 6] = accl;
    __syncthreads();
    if (t == 0) atomicAdd(loss_acc, wsum[0] + wsum[1] + wsum[2] + wsum[3]);
}

// ---------------------------------------------------------------- finalize
__global__ void finalize_kernel(const int* __restrict__ counts,
                                const float* __restrict__ loss_acc,
                                float* __restrict__ out_scalars)
{
    const int t = threadIdx.x;
    double s = 0.0;
    for (int n = t; n < N_CODES; n += 256) {
        double p = (double)counts[n] / (double)M_TOTAL;
        s -= p * log(p + 1e-10);
    }
#pragma unroll
    for (int off = 32; off >= 1; off >>= 1) s += __shfl_xor(s, off);
    __shared__ double sds[4];
    if ((t & 63) == 0) sds[t >> 6] = s;
    __syncthreads();
    if (t == 0) {
        double tot = sds[0] + sds[1] + sds[2] + sds[3];
        out_scalars[0] = (float)(0.25 * (double)(*loss_acc) / (double)(M_TOTAL * KDIM));
        out_scalars[1] = (float)exp(tot);
    }
}

// ---------------------------------------------------------------- launch
extern "C" void kernel_launch(void* const* d_in, const int* in_sizes, int n_in,
                              void* d_out, int out_size, void* d_ws, size_t ws_size,
                              hipStream_t stream) {
    const float* z      = (const float*)d_in[0];   // 4*256*16*16*16
    const float* weight = (const float*)d_in[1];   // 8192*256
    float* out = (float*)d_out;

    size_t off = 0;
    auto carve = [&](size_t bytes) {
        void* p = (char*)d_ws + off;
        off += (bytes + 255) & ~(size_t)255;
        return p;
    };
    _Float16* wpk    = (_Float16*)carve((size_t)N_CODES * KDIM * 2 * 2);  // 8 MB packed hi+lo
    float*    wsq    = (float*)   carve((size_t)N_CODES * 4);
    float*    t2v1   = (float*)   carve((size_t)NSPLIT * M_TOTAL * 4);
    int*      t2i1   = (int*)     carve((size_t)NSPLIT * M_TOTAL * 4);
    float*    t2v2   = (float*)   carve((size_t)NSPLIT * M_TOTAL * 4);
    int*      t2i2   = (int*)     carve((size_t)NSPLIT * M_TOTAL * 4);
    int*      idxf   = (int*)     carve((size_t)M_TOTAL * 4);
    int*      counts = (int*)     carve((size_t)N_CODES * 4);
    float*    lossac = (float*)   carve(16);

    float* out_scalars = out + (size_t)4 * KDIM * SPATIAL;       // [loss, perplexity]
    float* out_idx_f   = out_scalars + 2;                        // 16384 idx as float

    init_kernel<<<dim3((N_CODES + 255) / 256), dim3(256), 0, stream>>>(counts, lossac);
    prep_w_kernel<<<dim3(N_CODES), dim3(64), 0, stream>>>(weight, wpk, wsq);
    gemm_argmin_kernel<<<dim3(M_TOTAL / 128 * NSPLIT), dim3(256), 0, stream>>>(
        z, wpk, wsq, t2v1, t2i1, t2v2, t2i2);
    combine_kernel<<<dim3(M_TOTAL / 256), dim3(256), 0, stream>>>(
        z, weight, t2v1, t2i1, t2v2, t2i2, idxf, counts, out_idx_f);
    gather_loss_kernel<<<dim3(M_TOTAL / 32), dim3(256), 0, stream>>>(
        z, weight, idxf, out, lossac);
    finalize_kernel<<<dim3(1), dim3(256), 0, stream>>>(counts, lossac, out_scalars);
}

// Round 3
// 224.847 us; speedup vs baseline: 5.2580x; 1.4168x over previous
//
#include <hip/hip_runtime.h>
#include <stdint.h>

// VQ-VAE forward on MI355X — round 3.
// d_out (fp32): out[4194304] | loss[1] | perplexity[1] | idx_as_float[16384]
//
// prep_w   : weight -> fp16 (hi only), chunk-packed+swizzled; wsqC = |w|^2 + 256;
//            zeroes counts/loss (ws is re-poisoned every call).
// gemm     : single-product fp16 MFMA scores; 8 splits (1 per XCD, 512KB fits L2);
//            64 rows/wave, 2-wave blocks, 4 blocks/CU; packed-key top-2 per split.
// finish   : fp64 rescore of all 16 candidates/row -> exact idx, counts atomics,
//            loss = sum of chosen true distances, gather weight[idx] -> out.
// finalize : perplexity + loss scale.

#define M_TOTAL 16384
#define N_CODES 8192
#define KDIM    256
#define SPATIAL 4096
#define NSPLIT  8
#define CODES_PER_SPLIT  1024
#define CHUNK_CODES      32
#define CHUNKS_PER_SPLIT 32
#define CHUNK_HALFS      8192     // 32 codes * 256 dims
#define CHUNK_BYTES      16384
#define SCORE_C          256.0f   // keeps packed scores strictly positive

typedef _Float16 v8hf __attribute__((ext_vector_type(8)));
typedef _Float16 v4hf __attribute__((ext_vector_type(4)));
typedef float    v4f  __attribute__((ext_vector_type(4)));

// ---------------------------------------------------------------- prep_w (+init)
// one wave per code row; writes hi-fp16 chunk-packed (32 codes = 16KB per chunk)
// with 16B-granule swizzle g ^= (code&7) so gemm's ds_read_b128 pattern is clean.
__global__ void prep_w_kernel(const float* __restrict__ w,
                              _Float16* __restrict__ wpk,
                              float* __restrict__ wsqC,
                              int* __restrict__ counts,
                              float* __restrict__ loss_acc) {
    int n = blockIdx.x;
    int lane = threadIdx.x;  // 64
    v4f v = ((const v4f*)(w + (size_t)n * KDIM))[lane];
    v4hf hv;
    float s = 0.0f;
#pragma unroll
    for (int j = 0; j < 4; j++) {
        float f = v[j];
        s += f * f;
        hv[j] = (_Float16)f;
    }
    const int d = lane * 4;          // element 0..255
    const int g = d >> 3;            // 16B granule 0..31
    const int sub = d & 7;
    size_t off = (size_t)(n >> 5) * CHUNK_HALFS
               + (size_t)(n & 31) * 256
               + ((g ^ (n & 7)) << 3) + sub;
    *(v4hf*)(wpk + off) = hv;
#pragma unroll
    for (int o = 32; o >= 1; o >>= 1) s += __shfl_xor(s, o);
    if (lane == 0) {
        wsqC[n] = s + SCORE_C;
        counts[n] = 0;
        if (n == 0) *loss_acc = 0.0f;
    }
}

// ---------------------------------------------------------------- uint top-2 merge
__device__ __forceinline__ void top2u_merge(uint32_t& v1, int& i1, uint32_t& v2, int& i2,
                                            uint32_t o1, int oi1, uint32_t o2, int oi2) {
    bool ob = (o1 < v1) || (o1 == v1 && oi1 < i1);
    uint32_t n1v, n2v; int n1i, n2i;
    if (ob) {
        bool t = (v1 < o2) || (v1 == o2 && i1 < oi2);
        n1v = o1; n1i = oi1;
        n2v = t ? v1 : o2; n2i = t ? i1 : oi2;
    } else {
        bool t = (o1 < v2) || (o1 == v2 && oi1 < i2);
        n1v = v1; n1i = i1;
        n2v = t ? o1 : v2; n2i = t ? oi1 : i2;
    }
    v1 = n1v; i1 = n1i; v2 = n2v; i2 = n2i;
}

// ---------------------------------------------------------------- gemm + split top-2
// grid 1024 = 128 row-blocks x 8 splits (split = bid&7 -> one split per XCD).
// block: 128 thr (2 waves), 128 rows (64/wave = 4 m-tiles). Sweeps its split's
// 1024 codes in 32 chunks of 32, hi-fp16 B double-buffered in LDS (2x16KB).
__global__ __launch_bounds__(128, 2) void gemm_kernel(
    const float* __restrict__ z,
    const _Float16* __restrict__ wpk,
    const float* __restrict__ wsqC,
    int* __restrict__ candbuf)
{
    __shared__ __align__(16) _Float16 ldsb[2][CHUNK_HALFS];   // 2 x 16KB

    const int bid   = blockIdx.x;
    const int split = bid & 7;
    const int rb    = bid >> 3;            // 0..127
    const int i0    = rb * 128;
    const int b     = i0 >> 12;
    const int s0    = i0 & (SPATIAL - 1);
    const int tid   = threadIdx.x;
    const int wave  = tid >> 6;
    const int lane  = tid & 63;
    const int r     = lane & 15;
    const int q     = lane >> 4;

    const char* wb = (const char*)wpk + (size_t)split * (CODES_PER_SPLIT * KDIM * 2);
    auto stage = [&](int chunk, int buf) {
        const char* gb = wb + (size_t)chunk * CHUNK_BYTES + wave * 8192 + lane * 16;
        _Float16* lb = &ldsb[buf][wave * 4096];
#pragma unroll
        for (int j = 0; j < 8; j++) {
            __builtin_amdgcn_global_load_lds(
                (const __attribute__((address_space(1))) void*)(gb + j * 1024),
                (__attribute__((address_space(3))) void*)(lb + j * 512), 16, 0, 0);
        }
    };
    stage(0, 0);

    // ---- A fragments: 4 m-tiles x 8 ks, hi only (128 VGPRs) ----
    v8hf a[4][8];
    {
        const float* zb = z + ((size_t)b << 20) + (size_t)(s0 + wave * 64 + r);
#pragma unroll
        for (int mt = 0; mt < 4; mt++) {
#pragma unroll
            for (int ks = 0; ks < 8; ks++) {
                const int kbase = ks * 32 + q * 8;
#pragma unroll
                for (int j = 0; j < 8; j++)
                    a[mt][ks][j] = (_Float16)zb[((size_t)(kbase + j) << 12) + mt * 16];
            }
        }
    }

    // packed-key top-2 state per (mt, g): low 6 bits carry (it<<1)|st
    uint32_t k1[4][4], k2[4][4];
#pragma unroll
    for (int mt = 0; mt < 4; mt++)
#pragma unroll
    for (int g = 0; g < 4; g++) { k1[mt][g] = 0xFFFFFFFFu; k2[mt][g] = 0xFFFFFFFFu; }

    const float* wsqS = wsqC + split * CODES_PER_SPLIT;
    const int swz = r & 7;

    for (int it = 0; it < CHUNKS_PER_SPLIT; it++) {
        const int buf = it & 1;
        __syncthreads();                        // chunk `it` landed, prev consumed
        if (it + 1 < CHUNKS_PER_SPLIT) stage(it + 1, buf ^ 1);

        v4f acc[4][2];
#pragma unroll
        for (int mt = 0; mt < 4; mt++)
#pragma unroll
        for (int st = 0; st < 2; st++) acc[mt][st] = (v4f){0.f, 0.f, 0.f, 0.f};

        const _Float16* L = &ldsb[buf][0];
#pragma unroll
        for (int st = 0; st < 2; st++) {
            const int rowoff = (st * 16 + r) * 256;     // halfs
#pragma unroll
            for (int ks = 0; ks < 8; ks++) {
                const int gran = ((ks << 2) | q) ^ swz;
                v8hf bh = *(const v8hf*)(L + rowoff + (gran << 3));
#pragma unroll
                for (int mt = 0; mt < 4; mt++)
                    acc[mt][st] = __builtin_amdgcn_mfma_f32_16x16x32_f16(a[mt][ks], bh, acc[mt][st], 0, 0, 0);
            }
        }

        // epilogue: score = |w|^2 + C - 2*dot (>0); pack tag in low 6 mantissa bits
#pragma unroll
        for (int st = 0; st < 2; st++) {
            const float wn = wsqS[(it << 5) + st * 16 + r];
            const uint32_t tag = (uint32_t)((it << 1) | st);
#pragma unroll
            for (int mt = 0; mt < 4; mt++)
#pragma unroll
            for (int g = 0; g < 4; g++) {
                float s = __builtin_fmaf(-2.0f, acc[mt][st][g], wn);
                uint32_t key = (__float_as_uint(s) & 0xFFFFFFC0u) | tag;
                uint32_t o1 = k1[mt][g], o2 = k2[mt][g];
                uint32_t hi = key > o1 ? key : o1;     // max
                k2[mt][g] = hi < o2 ? hi : o2;         // med3(o1,o2,key)
                k1[mt][g] = key < o1 ? key : o1;       // min
            }
        }
    }

    // decode n = split*1024 + (key&63)*16 + r, then cross-lane top-2 over 16 n-lanes
    const int nbase = split * CODES_PER_SPLIT + r;
#pragma unroll
    for (int mt = 0; mt < 4; mt++) {
#pragma unroll
        for (int g = 0; g < 4; g++) {
            uint32_t K1 = k1[mt][g], K2 = k2[mt][g];
            int n1 = nbase + (int)((K1 & 63u) << 4);
            int n2 = nbase + (int)((K2 & 63u) << 4);
#pragma unroll
            for (int off = 1; off < 16; off <<= 1) {
                uint32_t o1 = __shfl_xor(K1, off);
                int     on1 = __shfl_xor(n1, off);
                uint32_t o2 = __shfl_xor(K2, off);
                int     on2 = __shfl_xor(n2, off);
                top2u_merge(K1, n1, K2, n2, o1, on1, o2, on2);
            }
            if (r == 0) {
                const int row = i0 + wave * 64 + mt * 16 + q * 4 + g;
                candbuf[(size_t)row * 16 + split * 2]     = n1;
                candbuf[(size_t)row * 16 + split * 2 + 1] = n2;
            }
        }
    }
}

// ---------------------------------------------------------------- finish
// 512 blocks x 256 thr, 32 rows each: fp64 rescore of 16 candidates -> exact idx,
// counts atomics, loss = sum of chosen true distances, gather weight[idx] -> out.
__global__ __launch_bounds__(256) void finish_kernel(
    const float* __restrict__ z, const float* __restrict__ weight,
    const int* __restrict__ candbuf,
    int* __restrict__ counts, float* __restrict__ loss_acc,
    float* __restrict__ out, float* __restrict__ out_idx_f)
{
    __shared__ int s_cand[32][16];
    __shared__ int s_fi[32];
    __shared__ float s_w[32][257];     // 257: stride-1 banks for the write phase
    __shared__ double s_loss[4];

    const int i0 = blockIdx.x * 32;
    const int b  = i0 >> 12;
    const int s0 = i0 & (SPATIAL - 1);
    const int t  = threadIdx.x;

    for (int e = t; e < 32 * 16; e += 256)
        s_cand[e >> 4][e & 15] = candbuf[(size_t)(i0 + (e >> 4)) * 16 + (e & 15)];
    __syncthreads();

    // rescore: 8 threads/row, 32 dims each; z segment cached in registers
    const int row = t >> 3, seg = t & 7;
    const size_t zbase = ((size_t)b << 20) + (size_t)(s0 + row);
    float zs[32];
#pragma unroll
    for (int j = 0; j < 32; j++) zs[j] = z[zbase + ((size_t)(seg * 32 + j) << 12)];

    double dmin = 1e300; int nmin = 0x7fffffff;
    for (int c = 0; c < 16; c++) {
        const int n = s_cand[row][c];
        const float* wr = weight + (size_t)n * KDIM + seg * 32;
        double d = 0.0;
#pragma unroll
        for (int j = 0; j < 32; j++) {
            double df = (double)zs[j] - (double)wr[j];
            d += df * df;
        }
#pragma unroll
        for (int o = 1; o < 8; o <<= 1) d += __shfl_xor(d, o);   // all 8 segs get total
        if (d < dmin || (d == dmin && n < nmin)) { dmin = d; nmin = n; }
    }

    double lsum = 0.0;
    if (seg == 0) {
        s_fi[row] = nmin;
        out_idx_f[i0 + row] = (float)nmin;
        atomicAdd(&counts[nmin], 1);
        lsum = dmin;
    }
#pragma unroll
    for (int o = 1; o < 64; o <<= 1) lsum += __shfl_xor(lsum, o);
    if ((t & 63) == 0) s_loss[t >> 6] = lsum;
    __syncthreads();
    if (t == 0) atomicAdd(loss_acc, (float)(s_loss[0] + s_loss[1] + s_loss[2] + s_loss[3]));

    // gather weight[fi] -> LDS -> transposed coalesced write
    for (int e = t; e < 32 * KDIM; e += 256) {
        int rr = e >> 8, c = e & 255;
        s_w[rr][c] = weight[(size_t)s_fi[rr] * KDIM + c];
    }
    __syncthreads();
    const int m = t & 31, c0 = t >> 5;
    const size_t obase = ((size_t)b << 20) + (size_t)(s0 + m);
    for (int c = c0; c < KDIM; c += 8)
        out[obase + ((size_t)c << 12)] = s_w[m][c];
}

// ---------------------------------------------------------------- finalize
__global__ void finalize_kernel(const int* __restrict__ counts,
                                const float* __restrict__ loss_acc,
                                float* __restrict__ out_scalars)
{
    const int t = threadIdx.x;
    double s = 0.0;
    for (int n = t; n < N_CODES; n += 256) {
        double p = (double)counts[n] / (double)M_TOTAL;
        s -= p * log(p + 1e-10);
    }
#pragma unroll
    for (int o = 32; o >= 1; o >>= 1) s += __shfl_xor(s, o);
    __shared__ double sds[4];
    if ((t & 63) == 0) sds[t >> 6] = s;
    __syncthreads();
    if (t == 0) {
        double tot = sds[0] + sds[1] + sds[2] + sds[3];
        out_scalars[0] = (float)(0.25 * (double)(*loss_acc) / (double)(M_TOTAL * KDIM));
        out_scalars[1] = (float)exp(tot);
    }
}

// ---------------------------------------------------------------- launch
extern "C" void kernel_launch(void* const* d_in, const int* in_sizes, int n_in,
                              void* d_out, int out_size, void* d_ws, size_t ws_size,
                              hipStream_t stream) {
    const float* z      = (const float*)d_in[0];   // 4*256*16*16*16
    const float* weight = (const float*)d_in[1];   // 8192*256
    float* out = (float*)d_out;

    size_t off = 0;
    auto carve = [&](size_t bytes) {
        void* p = (char*)d_ws + off;
        off += (bytes + 255) & ~(size_t)255;
        return p;
    };
    _Float16* wpk     = (_Float16*)carve((size_t)N_CODES * KDIM * 2);   // 4 MB hi-only
    float*    wsqC    = (float*)   carve((size_t)N_CODES * 4);
    int*      candbuf = (int*)     carve((size_t)M_TOTAL * 16 * 4);     // 1 MB
    int*      counts  = (int*)     carve((size_t)N_CODES * 4);
    float*    lossac  = (float*)   carve(16);

    float* out_scalars = out + (size_t)4 * KDIM * SPATIAL;   // [loss, perplexity]
    float* out_idx_f   = out_scalars + 2;                    // 16384 idx as float

    prep_w_kernel<<<dim3(N_CODES), dim3(64), 0, stream>>>(weight, wpk, wsqC, counts, lossac);
    gemm_kernel<<<dim3(128 * NSPLIT), dim3(128), 0, stream>>>(z, wpk, wsqC, candbuf);
    finish_kernel<<<dim3(M_TOTAL / 32), dim3(256), 0, stream>>>(
        z, weight, candbuf, counts, lossac, out, out_idx_f);
    finalize_kernel<<<dim3(1), dim3(256), 0, stream>>>(counts, lossac, out_scalars);
}

// Round 4
// 209.776 us; speedup vs baseline: 5.6357x; 1.0718x over previous
//
#include <hip/hip_runtime.h>
#include <stdint.h>

// VQ-VAE forward on MI355X — round 4.
// d_out (fp32): out[4194304] | loss[1] | perplexity[1] | idx_as_float[16384]
//
// prep_w   : weight -> fp16 chunk-packed (16 codes = 8KB data + 64B hw bias + pad,
//            9216B stride) with 16B-granule swizzle; hw = 1024 - |w|^2/2 folded into
//            the MFMA C-init; zeroes counts/loss.
// gemm     : BARRIER-FREE. 1-wave blocks (64 rows), wave-private double-buffered LDS
//            staged via global_load_lds(16B), self-paced s_waitcnt vmcnt(9)/lgkmcnt(0).
//            8 splits XCD-pinned; packed-key (acc-bits|chunk-tag) top-2 MAX per split.
// finish   : prune candidates by approx score (margin 0.5), fp64 rescore survivors ->
//            exact idx, counts, loss; gather weight[idx] -> out (LDS transposed).
// finalize : perplexity + loss scale.

#define M_TOTAL 16384
#define N_CODES 8192
#define KDIM    256
#define SPATIAL 4096
#define NSPLIT  8
#define CODES_PER_SPLIT  1024
#define CHUNK_CODES      16
#define CHUNKS_PER_SPLIT 64
#define CHUNK_BYTES      9216       // 8192 data + 64 hw + 960 pad
#define CHUNK_HALFS      4608

typedef _Float16 v8hf __attribute__((ext_vector_type(8)));
typedef _Float16 v4hf __attribute__((ext_vector_type(4)));
typedef float    v4f  __attribute__((ext_vector_type(4)));

// s_waitcnt imm (gfx9 encoding): [3:0] vmcnt lo, [6:4] expcnt, [11:8] lgkmcnt, [15:14] vmcnt hi
#define WAITCNT_VM9   0x0F79   // vmcnt(9),  lgkm/exp no-wait
#define WAITCNT_VM0   0x0F70   // vmcnt(0),  lgkm/exp no-wait
#define WAITCNT_LGKM0 0xC07F   // lgkmcnt(0), vm/exp no-wait

// ---------------------------------------------------------------- prep_w (+init)
// 2048 blocks x 256 thr; one wave per code row.
__global__ __launch_bounds__(256) void prep_w_kernel(
    const float* __restrict__ w, _Float16* __restrict__ wpk,
    int* __restrict__ counts, double* __restrict__ loss_acc)
{
    const int t = threadIdx.x;
    const int n = blockIdx.x * 4 + (t >> 6);
    const int lane = t & 63;
    v4f v = ((const v4f*)(w + (size_t)n * KDIM))[lane];
    v4hf hv;
    float s = 0.0f;
#pragma unroll
    for (int j = 0; j < 4; j++) {
        float f = v[j];
        s += f * f;
        hv[j] = (_Float16)f;
    }
    const int chunk = n >> 4;
    const int row   = n & 15;
    const int g     = lane >> 1;               // 16B granule 0..31
    const int gg    = g ^ (n & 7);             // swizzle
    size_t off = (size_t)chunk * CHUNK_HALFS + row * 256 + gg * 8 + (lane & 1) * 4;
    *(v4hf*)(wpk + off) = hv;
#pragma unroll
    for (int o = 32; o >= 1; o >>= 1) s += __shfl_xor(s, o);
    if (lane == 0) {
        float* hwp = (float*)((char*)wpk + (size_t)chunk * CHUNK_BYTES + 8192);
        hwp[row] = 1024.0f - 0.5f * s;         // C-init bias: acc = hw + dot > 0
    }
    const int gi = blockIdx.x * 256 + t;
    if (gi < N_CODES) counts[gi] = 0;
    if (gi == 0) *loss_acc = 0.0;
}

// ---------------------------------------------------------------- top-2 MAX merge (key desc, n asc on tie)
__device__ __forceinline__ void top2max_merge(uint32_t& v1, int& i1, uint32_t& v2, int& i2,
                                              uint32_t o1, int oi1, uint32_t o2, int oi2) {
    bool ob = (o1 > v1) || (o1 == v1 && oi1 < i1);
    uint32_t n1v, n2v; int n1i, n2i;
    if (ob) {
        bool t2 = (v1 > o2) || (v1 == o2 && i1 < oi2);
        n1v = o1; n1i = oi1;
        n2v = t2 ? v1 : o2; n2i = t2 ? i1 : oi2;
    } else {
        bool t2 = (o1 > v2) || (o1 == v2 && oi1 < i2);
        n1v = v1; n1i = i1;
        n2v = t2 ? o1 : v2; n2i = t2 ? oi1 : i2;
    }
    v1 = n1v; i1 = n1i; v2 = n2v; i2 = n2i;
}

// ---------------------------------------------------------------- gemm (barrier-free)
// grid 2048 = 256 row-blocks x 8 splits; block = 1 wave, 64 rows (mt=4).
__global__ __launch_bounds__(64, 2) void gemm_kernel(
    const float* __restrict__ z,
    const _Float16* __restrict__ wpk,
    int4* __restrict__ candbuf)          // [M_TOTAL][8] = {k1,n1,k2,n2}
{
    __shared__ __align__(16) _Float16 lds[2][CHUNK_HALFS];   // 2 x 9216 B

    const int bid   = blockIdx.x;
    const int split = bid & 7;
    const int rb    = bid >> 3;            // 0..255
    const int i0    = rb * 64;
    const int b     = i0 >> 12;
    const int s0    = i0 & (SPATIAL - 1);
    const int lane  = threadIdx.x;
    const int r     = lane & 15;
    const int q     = lane >> 4;

    const char* wsplit = (const char*)wpk + (size_t)split * CHUNKS_PER_SPLIT * CHUNK_BYTES;
    auto stage = [&](int chunk, int buf) {
        const char* gb = wsplit + (size_t)chunk * CHUNK_BYTES + lane * 16;
        _Float16* lb = &lds[buf][lane * 8];
#pragma unroll
        for (int j = 0; j < 9; j++) {
            __builtin_amdgcn_global_load_lds(
                (const __attribute__((address_space(1))) void*)(gb + j * 1024),
                (__attribute__((address_space(3))) void*)(lb + j * 512), 16, 0, 0);
        }
    };
    stage(0, 0);
    stage(1, 1);

    // ---- A fragments: 4 m-tiles x 8 ks (128 VGPRs); loads overlap stage latency ----
    v8hf a[4][8];
    {
        const float* zb = z + ((size_t)b << 20) + (size_t)(s0 + r);
#pragma unroll
        for (int mt = 0; mt < 4; mt++) {
#pragma unroll
            for (int ks = 0; ks < 8; ks++) {
                const int kbase = ks * 32 + q * 8;
#pragma unroll
                for (int j = 0; j < 8; j++)
                    a[mt][ks][j] = (_Float16)zb[((size_t)(kbase + j) << 12) + mt * 16];
            }
        }
    }

    uint32_t k1[4][4], k2[4][4];
#pragma unroll
    for (int mt = 0; mt < 4; mt++)
#pragma unroll
    for (int g = 0; g < 4; g++) { k1[mt][g] = 0u; k2[mt][g] = 0u; }

    const int swz = r & 7;

    auto body = [&](int it, int buf) {
        // hw bias (fp32) for this chunk's 16 codes, at byte 8192 + r*4
        const float hwv = *(const float*)((const char*)&lds[buf][0] + 8192 + r * 4);
        v4f acc[4];
#pragma unroll
        for (int mt = 0; mt < 4; mt++) acc[mt] = (v4f){hwv, hwv, hwv, hwv};

        const _Float16* L = &lds[buf][0];
#pragma unroll
        for (int ks = 0; ks < 8; ks++) {
            const int gran = ((ks << 2) | q) ^ swz;
            v8hf bh = *(const v8hf*)(L + r * 256 + (gran << 3));
#pragma unroll
            for (int mt = 0; mt < 4; mt++)
                acc[mt] = __builtin_amdgcn_mfma_f32_16x16x32_f16(a[mt][ks], bh, acc[mt], 0, 0, 0);
        }
        // top-2 MAX of packed key: acc bits (distance = 2048 - 2*acc) | 6-bit chunk tag
        const uint32_t tag = (uint32_t)it;
#pragma unroll
        for (int mt = 0; mt < 4; mt++)
#pragma unroll
        for (int g = 0; g < 4; g++) {
            uint32_t key = (__float_as_uint(acc[mt][g]) & 0xFFFFFFC0u) | tag;
            uint32_t o1 = k1[mt][g], o2 = k2[mt][g];
            uint32_t hi = key > o2 ? key : o2;
            k2[mt][g] = hi < o1 ? hi : o1;      // med3(key, k1, k2)
            k1[mt][g] = key > o1 ? key : o1;
        }
    };

#pragma unroll 1
    for (int it = 0; it < CHUNKS_PER_SPLIT - 1; it++) {
        const int buf = it & 1;
        __builtin_amdgcn_s_waitcnt(WAITCNT_VM9);    // stage(it) landed (it+1 in flight)
        body(it, buf);
        __builtin_amdgcn_s_waitcnt(WAITCNT_LGKM0);  // ds_reads of buf drained
        if (it < CHUNKS_PER_SPLIT - 2) stage(it + 2, buf);
    }
    __builtin_amdgcn_s_waitcnt(WAITCNT_VM0);
    body(CHUNKS_PER_SPLIT - 1, (CHUNKS_PER_SPLIT - 1) & 1);

    // decode n, cross-lane top-2 over the 16 r-lanes, write per-split candidates
    const int nsbase = split * CODES_PER_SPLIT + r;
#pragma unroll
    for (int mt = 0; mt < 4; mt++) {
#pragma unroll
        for (int g = 0; g < 4; g++) {
            uint32_t K1 = k1[mt][g], K2 = k2[mt][g];
            int n1 = nsbase + (int)((K1 & 63u) << 4);
            int n2 = nsbase + (int)((K2 & 63u) << 4);
#pragma unroll
            for (int off = 1; off < 16; off <<= 1) {
                uint32_t o1 = __shfl_xor(K1, off);
                int     on1 = __shfl_xor(n1, off);
                uint32_t o2 = __shfl_xor(K2, off);
                int     on2 = __shfl_xor(n2, off);
                top2max_merge(K1, n1, K2, n2, o1, on1, o2, on2);
            }
            if (r == 0) {
                const int row = i0 + mt * 16 + q * 4 + g;
                candbuf[(size_t)row * 8 + split] = make_int4((int)K1, n1, (int)K2, n2);
            }
        }
    }
}

// ---------------------------------------------------------------- finish
// 512 blocks x 256 thr, 32 rows: prune by approx score, fp64 rescore survivors,
// exact idx + counts + loss; gather weight[idx] -> out.
__global__ __launch_bounds__(256) void finish_kernel(
    const float* __restrict__ z, const float* __restrict__ weight,
    const int4* __restrict__ candbuf,
    int* __restrict__ counts, double* __restrict__ loss_acc,
    float* __restrict__ out, float* __restrict__ out_idx_f)
{
    __shared__ int4  s_cand[32][8];
    __shared__ float s_zw[32][KDIM + 1];
    __shared__ int   s_fi[32];
    __shared__ double s_loss[4];

    const int i0 = blockIdx.x * 32;
    const int b  = i0 >> 12;
    const int s0 = i0 & (SPATIAL - 1);
    const int t  = threadIdx.x;

    s_cand[t >> 3][t & 7] = candbuf[(size_t)(i0 + (t >> 3)) * 8 + (t & 7)];

    // z tile transpose: coalesced global -> LDS
    for (int e = t; e < 32 * KDIM; e += 256) {
        const int c = e >> 5, rr = e & 31;
        s_zw[rr][c] = z[((size_t)b << 20) + ((size_t)c << 12) + s0 + rr];
    }
    __syncthreads();

    const int row = t >> 3, seg = t & 7;
    float zs[32];
#pragma unroll
    for (int j = 0; j < 32; j++) zs[j] = s_zw[row][seg * 32 + j];

    // approx distances + min
    float da[16];
    float dmin_a = 3.4e38f;
#pragma unroll
    for (int sp = 0; sp < 8; sp++) {
        int4 c = s_cand[row][sp];
        da[sp * 2]     = 2048.0f - 2.0f * __uint_as_float((uint32_t)c.x & 0xFFFFFFC0u);
        da[sp * 2 + 1] = 2048.0f - 2.0f * __uint_as_float((uint32_t)c.z & 0xFFFFFFC0u);
        dmin_a = fminf(dmin_a, fminf(da[sp * 2], da[sp * 2 + 1]));
    }
    const float cutoff = dmin_a + 0.5f;

    double dbest = 1e300; int nbest = 0x7fffffff;
#pragma unroll 1
    for (int c = 0; c < 16; c++) {
        if (da[c] > cutoff) continue;
        int4 cc = s_cand[row][c >> 1];
        const int n = (c & 1) ? cc.w : cc.y;
        const float* wr = weight + (size_t)n * KDIM + seg * 32;
        double d = 0.0;
#pragma unroll
        for (int j = 0; j < 32; j++) {
            double df = (double)zs[j] - (double)wr[j];
            d += df * df;
        }
#pragma unroll
        for (int o = 1; o < 8; o <<= 1) d += __shfl_xor(d, o);
        if (d < dbest || (d == dbest && n < nbest)) { dbest = d; nbest = n; }
    }

    double lsum = 0.0;
    if (seg == 0) {
        s_fi[row] = nbest;
        out_idx_f[i0 + row] = (float)nbest;
        atomicAdd(&counts[nbest], 1);
        lsum = dbest;
    }
#pragma unroll
    for (int o = 1; o < 64; o <<= 1) lsum += __shfl_xor(lsum, o);
    if ((t & 63) == 0) s_loss[t >> 6] = lsum;
    __syncthreads();
    if (t == 0) atomicAdd(loss_acc, s_loss[0] + s_loss[1] + s_loss[2] + s_loss[3]);

    // gather weight[fi] -> LDS (reuse s_zw) -> transposed coalesced write
    for (int e = t; e < 32 * KDIM; e += 256) {
        const int rr = e >> 8, c = e & 255;
        s_zw[rr][c] = weight[(size_t)s_fi[rr] * KDIM + c];
    }
    __syncthreads();
    const int m = t & 31, c0 = t >> 5;
    const size_t obase = ((size_t)b << 20) + (size_t)(s0 + m);
    for (int c = c0; c < KDIM; c += 8)
        out[obase + ((size_t)c << 12)] = s_zw[m][c];
}

// ---------------------------------------------------------------- finalize
__global__ void finalize_kernel(const int* __restrict__ counts,
                                const double* __restrict__ loss_acc,
                                float* __restrict__ out_scalars)
{
    const int t = threadIdx.x;
    double s = 0.0;
    for (int n = t; n < N_CODES; n += 256) {
        double p = (double)counts[n] / (double)M_TOTAL;
        s -= p * log(p + 1e-10);
    }
#pragma unroll
    for (int o = 32; o >= 1; o >>= 1) s += __shfl_xor(s, o);
    __shared__ double sds[4];
    if ((t & 63) == 0) sds[t >> 6] = s;
    __syncthreads();
    if (t == 0) {
        double tot = sds[0] + sds[1] + sds[2] + sds[3];
        out_scalars[0] = (float)(0.25 * (*loss_acc) / (double)(M_TOTAL * KDIM));
        out_scalars[1] = (float)exp(tot);
    }
}

// ---------------------------------------------------------------- launch
extern "C" void kernel_launch(void* const* d_in, const int* in_sizes, int n_in,
                              void* d_out, int out_size, void* d_ws, size_t ws_size,
                              hipStream_t stream) {
    const float* z      = (const float*)d_in[0];   // 4*256*16*16*16
    const float* weight = (const float*)d_in[1];   // 8192*256
    float* out = (float*)d_out;

    size_t off = 0;
    auto carve = [&](size_t bytes) {
        void* p = (char*)d_ws + off;
        off += (bytes + 255) & ~(size_t)255;
        return p;
    };
    _Float16* wpk     = (_Float16*)carve((size_t)(N_CODES / CHUNK_CODES) * CHUNK_BYTES); // 4.72 MB
    int4*     candbuf = (int4*)    carve((size_t)M_TOTAL * 8 * 16);                      // 2 MB
    int*      counts  = (int*)     carve((size_t)N_CODES * 4);
    double*   lossac  = (double*)  carve(16);

    float* out_scalars = out + (size_t)4 * KDIM * SPATIAL;   // [loss, perplexity]
    float* out_idx_f   = out_scalars + 2;                    // 16384 idx as float

    prep_w_kernel<<<dim3(N_CODES / 4), dim3(256), 0, stream>>>(weight, wpk, counts, lossac);
    gemm_kernel<<<dim3(M_TOTAL / 64 * NSPLIT), dim3(64), 0, stream>>>(z, wpk, candbuf);
    finish_kernel<<<dim3(M_TOTAL / 32), dim3(256), 0, stream>>>(
        z, weight, candbuf, counts, lossac, out, out_idx_f);
    finalize_kernel<<<dim3(1), dim3(256), 0, stream>>>(counts, lossac, out_scalars);
}